// Round 13
// baseline (478.085 us; speedup 1.0000x reference)
//
#include <hip/hip_runtime.h>
#include <hip/hip_bf16.h>

using f32x4 = __attribute__((ext_vector_type(4))) float;
using s16x8 = __attribute__((ext_vector_type(8))) short;
typedef unsigned short u16;

__device__ __forceinline__ u16 f2bf(float f) {
    return __bfloat16_as_ushort(__float2bfloat16(f));
}

// ---------------- weight transpose + bf16 convert: wt[n*K+k] = w[k*N+n] ----
__global__ void wconv_t(const float* __restrict__ w, __hip_bfloat16* __restrict__ wt,
                        int K, int N) {
    int idx = blockIdx.x * 256 + threadIdx.x;
    if (idx >= K * N) return;
    int n = idx / K, k = idx - n * K;
    wt[idx] = __float2bfloat16(w[(long)k * N + n]);
}

// ---------------- ada = silu(c) @ ada_w + ada_b   (16 x 1536) --------------
__global__ __launch_bounds__(256) void ada_kernel(const float* __restrict__ c,
                                                  const float* __restrict__ ada_w,
                                                  const float* __restrict__ ada_b,
                                                  float* __restrict__ ada) {
    __shared__ float sc[16 * 256];
    int tid = threadIdx.x;
    for (int i = tid; i < 16 * 256; i += 256) {
        float v = c[i];
        sc[i] = v / (1.0f + expf(-v));
    }
    __syncthreads();
    int j = blockIdx.x * 256 + tid;   // grid = 6 -> j in [0,1536)
    float b = ada_b[j];
    for (int n = 0; n < 16; n++) {
        float acc = b;
        for (int k = 0; k < 256; k++)
            acc += sc[n * 256 + k] * ada_w[(long)k * 1536 + j];
        ada[n * 1536 + j] = acc;
    }
}

// ---------------- full Swin block, one kernel per window -------------------
// Block = 1 window (64 tokens), 512 thr / 8 waves.
// Phase A (attn, round-11 proven): wave = head h.
//   LN1 -> xa | QKV (W from L2) -> qk/vt | S=QK^T | softmax | P->qk swz |
//   O=PV -> xa | proj -> out1 (f32, LDS overlay on qk, stride 260 dw).
// Phase B (mlp, round-10 proven): wave = (row-half s, col-quarter w2).
//   LN2(out1 LDS) -> xa | 4x{fc1-chunk -> gelu -> hb(vt overlay, 268) ->
//   fc2-chunk accum} | out = out1 + g*(acc2+b2) -> d_out (single write).
// out1 / h1 NEVER touch HBM. LDS 145.4 KB -> 1 block/CU, 8 waves.
__global__ __launch_bounds__(512) void swin_mega(const float* __restrict__ x_seq,
                                                 const __hip_bfloat16* __restrict__ qkvw,
                                                 const float* __restrict__ qkv_b,
                                                 const __hip_bfloat16* __restrict__ projw,
                                                 const float* __restrict__ proj_b,
                                                 const float* __restrict__ rpb,
                                                 const float* __restrict__ ada,
                                                 const __hip_bfloat16* __restrict__ fc1w,
                                                 const float* __restrict__ fc1_b,
                                                 const __hip_bfloat16* __restrict__ fc2w,
                                                 const float* __restrict__ fc2_b,
                                                 float* __restrict__ outf) {
    __shared__ u16 xa[64 * 264];     // LN'd x -> O -> LN2'd out1
    __shared__ u16 qk[2 * 64 * 264]; // Q|K -> P(h*4096, swz) -> out1 f32 overlay
    __shared__ u16 vt[8][32 * 72];   // V^T -> hb overlay (stride 268)
    __shared__ float bs[8 * 225];    // compact rel-pos bias

    int tid = threadIdx.x;
    int lane = tid & 63;
    int wv = tid >> 6;               // 0..7
    int h = wv;                      // phase A: wave == head
    int la = lane & 15, lb = lane >> 4;
    int win = blockIdx.x;
    int n = win >> 6, wh = (win >> 3) & 7, ww = win & 7;
    long base = (long)n * 4096 + (long)(wh * 8) * 64 + ww * 8;

    for (int i = tid; i < 1800; i += 512) bs[i] = rpb[(i % 225) * 8 + (i / 225)];

    // ---- LN1 + modulate: wave h owns rows t = h*8 .. h*8+7 ----
    {
        const float* shp = &ada[n * 1536 + 0];
        const float* scp = &ada[n * 1536 + 256];
#pragma unroll
        for (int i = 0; i < 8; i++) {
            int t = h * 8 + i;
            long sr = base + h * 64 + i;
            const float4 v = *(const float4*)&x_seq[sr * 256 + lane * 4];
            float s = v.x + v.y + v.z + v.w;
            float s2 = v.x * v.x + v.y * v.y + v.z * v.z + v.w * v.w;
#pragma unroll
            for (int o = 32; o > 0; o >>= 1) {
                s += __shfl_xor(s, o, 64);
                s2 += __shfl_xor(s2, o, 64);
            }
            float mu = s * (1.0f / 256.0f);
            float var = s2 * (1.0f / 256.0f) - mu * mu;
            float rstd = rsqrtf(var + 1e-6f);
            float vv[4] = {v.x, v.y, v.z, v.w};
#pragma unroll
            for (int e = 0; e < 4; e++) {
                int col = lane * 4 + e;
                float val = (vv[e] - mu) * rstd;
                xa[t * 264 + col] = f2bf(val * (1.0f + scp[col]) + shp[col]);
            }
        }
    }
    __syncthreads();

    const u16* W = (const u16*)qkvw;   // [768][256]

    // ---- Q,K -> qk ; V -> vt (wave-local, 64 MFMA each) ----
#pragma unroll
    for (int m = 0; m < 3; m++) {
        const u16* Wm = W + (long)(m * 256 + h * 32) * 256;
        float bb0 = qkv_b[m * 256 + h * 32 + la];
        float bb1 = qkv_b[m * 256 + h * 32 + 16 + la];
        s16x8 bfr[2][8];
#pragma unroll
        for (int ct = 0; ct < 2; ct++)
#pragma unroll
            for (int kc = 0; kc < 8; kc++)
                bfr[ct][kc] = *(const s16x8*)&Wm[(ct * 16 + la) * 256 + kc * 32 + lb * 8];
        f32x4 acc[4][2] = {};
#pragma unroll
        for (int kc = 0; kc < 8; kc++) {
            s16x8 a[4];
#pragma unroll
            for (int rt = 0; rt < 4; rt++)
                a[rt] = *(const s16x8*)&xa[(rt * 16 + la) * 264 + kc * 32 + lb * 8];
#pragma unroll
            for (int rt = 0; rt < 4; rt++)
#pragma unroll
                for (int ct = 0; ct < 2; ct++)
                    acc[rt][ct] = __builtin_amdgcn_mfma_f32_16x16x32_bf16(
                        a[rt], bfr[ct][kc], acc[rt][ct], 0, 0, 0);
        }
        if (m < 2) {
            u16* dst = &qk[m * 16896];
#pragma unroll
            for (int rt = 0; rt < 4; rt++)
#pragma unroll
                for (int ct = 0; ct < 2; ct++)
#pragma unroll
                    for (int r = 0; r < 4; r++)
                        dst[(rt * 16 + lb * 4 + r) * 264 + h * 32 + ct * 16 + la] =
                            f2bf(acc[rt][ct][r] + (ct ? bb1 : bb0));
        } else {
#pragma unroll
            for (int rt = 0; rt < 4; rt++)
#pragma unroll
                for (int ct = 0; ct < 2; ct++)
#pragma unroll
                    for (int r = 0; r < 4; r++)
                        vt[h][(ct * 16 + la) * 72 + rt * 16 + lb * 4 + r] =
                            f2bf(acc[rt][ct][r] + (ct ? bb1 : bb0));
        }
    }
    __syncthreads();

    // ---- S = Q K^T ----
    s16x8 qf[4], kf[4];
#pragma unroll
    for (int rt = 0; rt < 4; rt++) {
        qf[rt] = *(const s16x8*)&qk[(rt * 16 + la) * 264 + h * 32 + lb * 8];
        kf[rt] = *(const s16x8*)&qk[16896 + (rt * 16 + la) * 264 + h * 32 + lb * 8];
    }
    f32x4 sa[4][4];
    f32x4 zero = {};
#pragma unroll
    for (int rt = 0; rt < 4; rt++)
#pragma unroll
        for (int ct = 0; ct < 4; ct++)
            sa[rt][ct] = __builtin_amdgcn_mfma_f32_16x16x32_bf16(qf[rt], kf[ct], zero, 0, 0, 0);

    // ---- softmax ----
    float rls[4][4];
    int jr = (la >> 3);
    int jc = la & 7;
#pragma unroll
    for (int rt = 0; rt < 4; rt++) {
#pragma unroll
        for (int r = 0; r < 4; r++) {
            int t = rt * 16 + lb * 4 + r;
            int tr = t >> 3, tc = t & 7;
            const float* bh = &bs[h * 225 + (tr + 7) * 15 + (tc - jc + 7)];
            float v0 = sa[rt][0][r] * 0.17677669529663687f + bh[-(0 * 2 + jr) * 15];
            float v1 = sa[rt][1][r] * 0.17677669529663687f + bh[-(1 * 2 + jr) * 15];
            float v2 = sa[rt][2][r] * 0.17677669529663687f + bh[-(2 * 2 + jr) * 15];
            float v3 = sa[rt][3][r] * 0.17677669529663687f + bh[-(3 * 2 + jr) * 15];
            float mx = fmaxf(fmaxf(v0, v1), fmaxf(v2, v3));
#pragma unroll
            for (int o = 1; o < 16; o <<= 1) mx = fmaxf(mx, __shfl_xor(mx, o, 64));
            float p0 = __expf(v0 - mx), p1 = __expf(v1 - mx);
            float p2 = __expf(v2 - mx), p3 = __expf(v3 - mx);
            float sum = (p0 + p1) + (p2 + p3);
#pragma unroll
            for (int o = 1; o < 16; o <<= 1) sum += __shfl_xor(sum, o, 64);
            sa[rt][0][r] = p0; sa[rt][1][r] = p1; sa[rt][2][r] = p2; sa[rt][3][r] = p3;
            rls[rt][r] = 1.0f / sum;
        }
    }
    __syncthreads();   // Q/K reads done -> region reusable

    // ---- P -> qk region (per-head 8KB, XOR-swizzled [64][64]) ----
    u16* P = &qk[h * 4096];
#pragma unroll
    for (int rt = 0; rt < 4; rt++)
#pragma unroll
        for (int ct = 0; ct < 4; ct++)
#pragma unroll
            for (int r = 0; r < 4; r++) {
                int t = rt * 16 + lb * 4 + r;
                int slot = ct * 2 + (la >> 3);
                P[t * 64 + ((slot ^ (t & 7)) << 3) + (la & 7)] = f2bf(sa[rt][ct][r]);
            }
    __syncthreads();

    // ---- O = P V -> xa ----
    f32x4 oa[4][2] = {};
#pragma unroll
    for (int ks = 0; ks < 2; ks++) {
        s16x8 vf[2];
#pragma unroll
        for (int dt = 0; dt < 2; dt++)
            vf[dt] = *(const s16x8*)&vt[h][(dt * 16 + la) * 72 + ks * 32 + lb * 8];
#pragma unroll
        for (int rt = 0; rt < 4; rt++) {
            int t = rt * 16 + la;
            s16x8 pf = *(const s16x8*)&P[t * 64 + (((ks * 4 + lb) ^ (t & 7)) << 3)];
#pragma unroll
            for (int dt = 0; dt < 2; dt++)
                oa[rt][dt] = __builtin_amdgcn_mfma_f32_16x16x32_bf16(pf, vf[dt], oa[rt][dt], 0, 0, 0);
        }
    }
#pragma unroll
    for (int rt = 0; rt < 4; rt++)
#pragma unroll
        for (int dt = 0; dt < 2; dt++)
#pragma unroll
            for (int r = 0; r < 4; r++)
                xa[(rt * 16 + lb * 4 + r) * 264 + h * 32 + dt * 16 + la] =
                    f2bf(oa[rt][dt][r] * rls[rt][r]);
    __syncthreads();   // O ready; P/vt dead; qk free for out1

    float* o1 = (float*)qk;          // out1 f32 overlay, stride 260 dw

    // ---- proj -> out1 (LDS) ----
    {
        const u16* Pw = (const u16*)projw + (long)(h * 32) * 256;
        s16x8 bfr[2][8];
#pragma unroll
        for (int ct = 0; ct < 2; ct++)
#pragma unroll
            for (int kc = 0; kc < 8; kc++)
                bfr[ct][kc] = *(const s16x8*)&Pw[(ct * 16 + la) * 256 + kc * 32 + lb * 8];
        f32x4 pj[4][2] = {};
#pragma unroll
        for (int kc = 0; kc < 8; kc++) {
            s16x8 a[4];
#pragma unroll
            for (int rt = 0; rt < 4; rt++)
                a[rt] = *(const s16x8*)&xa[(rt * 16 + la) * 264 + kc * 32 + lb * 8];
#pragma unroll
            for (int rt = 0; rt < 4; rt++)
#pragma unroll
                for (int ct = 0; ct < 2; ct++)
                    pj[rt][ct] = __builtin_amdgcn_mfma_f32_16x16x32_bf16(
                        a[rt], bfr[ct][kc], pj[rt][ct], 0, 0, 0);
        }
        float g0 = ada[n * 1536 + 512 + h * 32 + la];
        float g1 = ada[n * 1536 + 512 + h * 32 + 16 + la];
        float pb0 = proj_b[h * 32 + la];
        float pb1 = proj_b[h * 32 + 16 + la];
#pragma unroll
        for (int rt = 0; rt < 4; rt++) {
#pragma unroll
            for (int r = 0; r < 4; r++) {
                int t = rt * 16 + lb * 4 + r;
                long sr = base + (t >> 3) * 64 + (t & 7);
#pragma unroll
                for (int ct = 0; ct < 2; ct++) {
                    int col = h * 32 + ct * 16 + la;
                    float v = pj[rt][ct][r] + (ct ? pb1 : pb0);
                    o1[t * 260 + col] = x_seq[sr * 256 + col] + (ct ? g1 : g0) * v;
                }
            }
        }
    }
    __syncthreads();   // out1 complete; xa (O) reads done -> xa reusable

    // ==================== Phase B: MLP ====================
    // ---- LN2 + modulate: wave wv owns rows t = wv*8 .. wv*8+7 ----
    {
        const float* shp = &ada[n * 1536 + 768];
        const float* scp = &ada[n * 1536 + 1024];
#pragma unroll
        for (int i = 0; i < 8; i++) {
            int t = wv * 8 + i;
            const float4 v = *(const float4*)&o1[t * 260 + lane * 4];
            float s = v.x + v.y + v.z + v.w;
            float s2 = v.x * v.x + v.y * v.y + v.z * v.z + v.w * v.w;
#pragma unroll
            for (int o = 32; o > 0; o >>= 1) {
                s += __shfl_xor(s, o, 64);
                s2 += __shfl_xor(s2, o, 64);
            }
            float mu = s * (1.0f / 256.0f);
            float var = s2 * (1.0f / 256.0f) - mu * mu;
            float rstd = rsqrtf(var + 1e-6f);
            float vv[4] = {v.x, v.y, v.z, v.w};
#pragma unroll
            for (int e = 0; e < 4; e++) {
                int col = lane * 4 + e;
                float val = (vv[e] - mu) * rstd;
                xa[t * 264 + col] = f2bf(val * (1.0f + scp[col]) + shp[col]);
            }
        }
    }
    __syncthreads();

    // ---- MLP: wave = (s2 = row-half, w2 = col-quarter) ----
    int s2 = wv >> 2;                // rows [(s2*2..s2*2+1)*16)
    int w2 = wv & 3;                 // cols [w2*64, +64)
    u16* hb = (u16*)vt;              // stride 268, proven conflict-free
    const u16* F1 = (const u16*)fc1w;   // [1024][256]
    const u16* F2 = (const u16*)fc2w;   // [256][1024]

    f32x4 acc2[2][4] = {};

#pragma unroll 1
    for (int c = 0; c < 4; c++) {
        f32x4 acc1[2][4] = {};
        const u16* B1 = F1 + (long)(c * 256 + w2 * 64) * 256;
        s16x8 bc[8];
#pragma unroll
        for (int ct = 0; ct < 4; ct++)
#pragma unroll
            for (int kk = 0; kk < 2; kk++)
                bc[ct * 2 + kk] = *(const s16x8*)&B1[(ct * 16 + la) * 256 + kk * 32 + lb * 8];
#pragma unroll
        for (int k0 = 0; k0 < 4; k0++) {
            s16x8 bn[8];
            if (k0 < 3) {
#pragma unroll
                for (int ct = 0; ct < 4; ct++)
#pragma unroll
                    for (int kk = 0; kk < 2; kk++)
                        bn[ct * 2 + kk] = *(const s16x8*)&B1[(ct * 16 + la) * 256 +
                                                             (k0 + 1) * 64 + kk * 32 + lb * 8];
            }
            s16x8 a[2][2];
#pragma unroll
            for (int q = 0; q < 2; q++)
#pragma unroll
                for (int kk = 0; kk < 2; kk++)
                    a[q][kk] = *(const s16x8*)&xa[((s2 * 2 + q) * 16 + la) * 264 +
                                                  k0 * 64 + kk * 32 + lb * 8];
            __builtin_amdgcn_s_setprio(1);
#pragma unroll
            for (int kk = 0; kk < 2; kk++)
#pragma unroll
                for (int q = 0; q < 2; q++)
#pragma unroll
                    for (int ct = 0; ct < 4; ct++)
                        acc1[q][ct] = __builtin_amdgcn_mfma_f32_16x16x32_bf16(
                            a[q][kk], bc[ct * 2 + kk], acc1[q][ct], 0, 0, 0);
            __builtin_amdgcn_s_setprio(0);
            if (k0 < 3) {
#pragma unroll
                for (int q2 = 0; q2 < 8; q2++) bc[q2] = bn[q2];
            }
        }
        // gelu -> hb (wave's 32 rows x 64 cols)
#pragma unroll
        for (int ct = 0; ct < 4; ct++) {
            float b1v = fc1_b[c * 256 + w2 * 64 + ct * 16 + la];
#pragma unroll
            for (int q = 0; q < 2; q++) {
#pragma unroll
                for (int r = 0; r < 4; r++) {
                    float v = acc1[q][ct][r] + b1v;
                    float u2 = 1.5957691216057308f * (v + 0.044715f * v * v * v);
                    hb[((s2 * 2 + q) * 16 + lb * 4 + r) * 268 + w2 * 64 + ct * 16 + la] =
                        f2bf(v / (1.0f + __expf(-u2)));
                }
            }
        }
        __syncthreads();

        const u16* B2 = F2 + (long)(w2 * 64) * 1024 + c * 256;
        s16x8 bc2[8];
#pragma unroll
        for (int ct = 0; ct < 4; ct++)
#pragma unroll
            for (int kk = 0; kk < 2; kk++)
                bc2[ct * 2 + kk] = *(const s16x8*)&B2[(ct * 16 + la) * 1024 + kk * 32 + lb * 8];
#pragma unroll
        for (int k0 = 0; k0 < 4; k0++) {
            s16x8 bn2[8];
            if (k0 < 3) {
#pragma unroll
                for (int ct = 0; ct < 4; ct++)
#pragma unroll
                    for (int kk = 0; kk < 2; kk++)
                        bn2[ct * 2 + kk] = *(const s16x8*)&B2[(ct * 16 + la) * 1024 +
                                                              (k0 + 1) * 64 + kk * 32 + lb * 8];
            }
            s16x8 a[2][2];
#pragma unroll
            for (int q = 0; q < 2; q++)
#pragma unroll
                for (int kk = 0; kk < 2; kk++)
                    a[q][kk] = *(const s16x8*)&hb[((s2 * 2 + q) * 16 + la) * 268 +
                                                  k0 * 64 + kk * 32 + lb * 8];
            __builtin_amdgcn_s_setprio(1);
#pragma unroll
            for (int kk = 0; kk < 2; kk++)
#pragma unroll
                for (int q = 0; q < 2; q++)
#pragma unroll
                    for (int ct = 0; ct < 4; ct++)
                        acc2[q][ct] = __builtin_amdgcn_mfma_f32_16x16x32_bf16(
                            a[q][kk], bc2[ct * 2 + kk], acc2[q][ct], 0, 0, 0);
            __builtin_amdgcn_s_setprio(0);
            if (k0 < 3) {
#pragma unroll
                for (int q2 = 0; q2 < 8; q2++) bc2[q2] = bn2[q2];
            }
        }
        __syncthreads();
    }

    // ---- final: out = out1 + g_mlp * (acc2 + fc2_b) -> d_out (one write) --
#pragma unroll
    for (int ct = 0; ct < 4; ct++) {
        int col = w2 * 64 + ct * 16 + la;
        float g = ada[n * 1536 + 1280 + col];
        float b2v = fc2_b[col];
#pragma unroll
        for (int q = 0; q < 2; q++) {
#pragma unroll
            for (int r = 0; r < 4; r++) {
                int t = (s2 * 2 + q) * 16 + lb * 4 + r;
                long sr = base + (t >> 3) * 64 + (t & 7);
                outf[sr * 256 + col] = o1[t * 260 + col] + g * (acc2[q][ct][r] + b2v);
            }
        }
    }
}

// ---------------------------------------------------------------------------
extern "C" void kernel_launch(void* const* d_in, const int* in_sizes, int n_in,
                              void* d_out, int out_size, void* d_ws, size_t ws_size,
                              hipStream_t stream) {
    const float* x_seq  = (const float*)d_in[0];
    const float* c      = (const float*)d_in[1];
    const float* qkv_w  = (const float*)d_in[2];
    const float* qkv_b  = (const float*)d_in[3];
    const float* proj_w = (const float*)d_in[4];
    const float* proj_b = (const float*)d_in[5];
    const float* rpb    = (const float*)d_in[6];
    const float* ada_w  = (const float*)d_in[7];
    const float* ada_b  = (const float*)d_in[8];
    const float* fc1_w  = (const float*)d_in[9];
    const float* fc1_b  = (const float*)d_in[10];
    const float* fc2_w  = (const float*)d_in[11];
    const float* fc2_b  = (const float*)d_in[12];

    char* ws = (char*)d_ws;
    float* ada             = (float*)ws;                       // 96 KB
    __hip_bfloat16* qkv_wt = (__hip_bfloat16*)(ws + 131072);   // 768x256 bf16
    __hip_bfloat16* proj_wt= (__hip_bfloat16*)(ws + 524288);   // 256x256
    __hip_bfloat16* fc1_wt = (__hip_bfloat16*)(ws + 655360);   // 1024x256
    __hip_bfloat16* fc2_wt = (__hip_bfloat16*)(ws + 1179648);  // 256x1024
    float* outf = (float*)d_out;

    wconv_t<<<(256 * 768 + 255) / 256, 256, 0, stream>>>(qkv_w, qkv_wt, 256, 768);
    wconv_t<<<(256 * 256 + 255) / 256, 256, 0, stream>>>(proj_w, proj_wt, 256, 256);
    wconv_t<<<(256 * 1024 + 255) / 256, 256, 0, stream>>>(fc1_w, fc1_wt, 256, 1024);
    wconv_t<<<(1024 * 256 + 255) / 256, 256, 0, stream>>>(fc2_w, fc2_wt, 1024, 256);

    ada_kernel<<<6, 256, 0, stream>>>(c, ada_w, ada_b, ada);

    // whole Swin block, one kernel: LN1+qkv+attn+proj+LN2+MLP+residuals
    swin_mega<<<1024, 512, 0, stream>>>(x_seq, qkv_wt, qkv_b, proj_wt, proj_b,
                                        rpb, ada, fc1_wt, fc1_b, fc2_wt, fc2_b,
                                        outf);
}